// Round 1
// baseline (216.163 us; speedup 1.0000x reference)
//
#include <hip/hip_runtime.h>
#include <hip/hip_bf16.h>
#include <stdint.h>

typedef __hip_bfloat16 bf16;
typedef __attribute__((ext_vector_type(8))) short short8;   // 8 bf16 = 4 VGPRs (MFMA A/B frag)
typedef __attribute__((ext_vector_type(4))) float floatx4;  // MFMA C/D frag

#define AS1(p) ((const __attribute__((address_space(1))) void*)(p))
#define AS3(p) ((__attribute__((address_space(3))) void*)(p))

#define M_DIM 4096
#define H_DIM 1024
#define STAGE_BYTES 32768   // one K-step stage: A 16KB + B 16KB (4 stages = 128 KB)

// fp32 -> bf16 bits, round-to-nearest-even (inputs are finite)
__device__ __forceinline__ unsigned short f2bf(float f) {
    uint32_t u = __float_as_uint(f);
    uint32_t r = (u + 0x7FFFu + ((u >> 16) & 1u)) >> 16;
    return (unsigned short)r;
}

__device__ __forceinline__ float fast_sigmoid(float v) {
    return 1.0f / (1.0f + __expf(-v));
}
__device__ __forceinline__ float fast_tanh(float v) {
    return 2.0f / (1.0f + __expf(-2.0f * v)) - 1.0f;
}

// ---------------------------------------------------------------------------
// Kernel 1: PACK fp32 -> bf16 chunks in the exact swizzled LDS-image order the
// GEMM stages them.  One chunk = 1 KB = [16 rows][4 k-slots][8 bf16], where
// slot = kgroup ^ ((row>>1)&3) (bank-conflict swizzle, pre-baked).
// NEW chunk map (unified KT in [0,64) spans x-part then h-part so the GEMM
// walks K with ONE uniform stride — no phase-select math in the hot loop):
//   W in [0,16384):      A chunks, W = (mx*64 + KT)*16 + ch
//                        (mx<16 row-panel of 256, ch<16 row-group of 16)
//                        KT<32 -> x, KT>=32 -> h ; row = mx*256 + ch*16 + r
//   W in [16384,32768):  B chunks, W-16384 = (ny*16 + b)*64 + KT
//                        b = g*4 + c4 (gate g, col-group c4); KT<32 -> Wx_g,
//                        KT>=32 -> Wh_g ; row = ny*64 + c4*16 + r
// GEMM DMAs each chunk as base + lane*16 over CONTIGUOUS memory.
__global__ __launch_bounds__(256)
void pack_bf16(const float* __restrict__ x, const float* __restrict__ h,
               const float* Wxf, const float* Wxi, const float* Wxo, const float* Wxc,
               const float* Whf, const float* Whi, const float* Who, const float* Whc,
               unsigned short* __restrict__ ws)
{
    const int w = threadIdx.x >> 6;
    const int l = threadIdx.x & 63;
    const uint32_t W = blockIdx.x * 4u + (uint32_t)w;   // chunk id [0, 32768)

    const uint32_t r  = (uint32_t)l >> 2;                       // row in chunk [0,16)
    const uint32_t kg = ((uint32_t)l & 3u) ^ ((r >> 1) & 3u);   // k-group of this slot

    const float* src;
    uint32_t row, ktl;
    if (W < 16384u) {                    // A-chunks (x / h)
        const uint32_t ch = W & 15u;
        const uint32_t KT = (W >> 4) & 63u;
        const uint32_t mx = W >> 10;
        src = (KT < 32u) ? x : h;
        ktl = KT & 31u;
        row = mx * 256u + ch * 16u + r;
    } else {                             // B-chunks (Wx_g / Wh_g)
        const uint32_t V  = W & 16383u;
        const uint32_t KT = V & 63u;
        const uint32_t U  = V >> 6;      // ny*16 + b
        const uint32_t b  = U & 15u;
        const uint32_t ny = U >> 4;
        const uint32_t g  = b >> 2;
        const uint32_t c4 = b & 3u;
        if (KT < 32u)
            src = (g == 0) ? Wxf : (g == 1) ? Wxi : (g == 2) ? Wxo : Wxc;
        else
            src = (g == 0) ? Whf : (g == 1) ? Whi : (g == 2) ? Who : Whc;
        ktl = KT & 31u;
        row = ny * 64u + c4 * 16u + r;
    }
    const float* s = src + (size_t)row * 1024u + ktl * 32u + kg * 8u;
    const float4 v0 = *(const float4*)s;
    const float4 v1 = *(const float4*)(s + 4);
    short8 pk;
    pk[0] = (short)f2bf(v0.x); pk[1] = (short)f2bf(v0.y);
    pk[2] = (short)f2bf(v0.z); pk[3] = (short)f2bf(v0.w);
    pk[4] = (short)f2bf(v1.x); pk[5] = (short)f2bf(v1.y);
    pk[6] = (short)f2bf(v1.z); pk[7] = (short)f2bf(v1.w);
    *(short8*)(ws + (size_t)W * 512u + (uint32_t)l * 8u) = pk;
}

// ---------------------------------------------------------------------------
// Kernel 2: fused 4-gate GEMM + LSTM pointwise, m201-style phase schedule.
// Tile: 256 batch-rows x (4 gates x 64 cols).  Grid: 16x16 = 256 blocks,
// 1 block/CU (128 KB LDS).  8 waves = 2(M) x 4(N).  Per wave: 128 rows x
// (4 gates x 16 cols) -> acc[4][8] (128 VGPR).
// K = 2048 in 64 steps of 32.  4-stage LDS ring, depth-3 prefetch.
// Per step, 2 phases of {ds_read ; 2 DMA ; barrier ; lgkmcnt(0) ; setprio(1)
// ; 16 MFMA ; setprio(0) ; barrier}; counted vmcnt(8) once per step.
#define GLL(srcp, dstp) __builtin_amdgcn_global_load_lds(AS1(srcp), AS3(dstp), 16, 0, 0)

#define VMW8 asm volatile("s_waitcnt vmcnt(8)" ::: "memory")
#define VMW4 asm volatile("s_waitcnt vmcnt(4)" ::: "memory")
#define VMW0 asm volatile("s_waitcnt vmcnt(0)" ::: "memory")
#define VMNONE ((void)0)

#define ITER(kt_, ISSUE_, VMA_)                                                   \
  {                                                                               \
    const uint32_t sc_ = (uint32_t)(kt_) & 3u;                                    \
    const uint32_t sl_ = (uint32_t)((kt_) + 3) & 3u;                              \
    const bf16* base_ = (const bf16*)(lds + sc_ * STAGE_BYTES);                   \
    char* ldst_ = lds + sl_ * STAGE_BYTES;                                        \
    short8 bfr_[4], afr_[4];                                                      \
    _Pragma("unroll") for (int g_ = 0; g_ < 4; ++g_)                              \
        bfr_[g_] = *(const short8*)(base_ + boff[g_]);                            \
    _Pragma("unroll") for (int m_ = 0; m_ < 4; ++m_)                              \
        afr_[m_] = *(const short8*)(base_ + aoff[m_]);                            \
    if (ISSUE_) { GLL(srcP[0] + ko0, ldst_ + loffA[0]);                           \
                  GLL(srcP[1] + ko1, ldst_ + loffA[1]); }                         \
    __builtin_amdgcn_s_barrier();                                                 \
    asm volatile("s_waitcnt lgkmcnt(0)" ::: "memory");                            \
    __builtin_amdgcn_sched_barrier(0);                                            \
    __builtin_amdgcn_s_setprio(1);                                                \
    _Pragma("unroll") for (int g_ = 0; g_ < 4; ++g_)                              \
      _Pragma("unroll") for (int m_ = 0; m_ < 4; ++m_)                            \
        acc[g_][m_] = __builtin_amdgcn_mfma_f32_16x16x32_bf16(                    \
            afr_[m_], bfr_[g_], acc[g_][m_], 0, 0, 0);                            \
    __builtin_amdgcn_s_setprio(0);                                                \
    __builtin_amdgcn_s_barrier();                                                 \
    _Pragma("unroll") for (int m_ = 0; m_ < 4; ++m_)                              \
        afr_[m_] = *(const short8*)(base_ + aoff[4 + m_]);                        \
    if (ISSUE_) { GLL(srcP[2] + ko2, ldst_ + loffA[2]);                           \
                  GLL(srcP[3] + ko3, ldst_ + loffA[3]);                           \
                  ko0 += kstr0; ko1 += kstr1; ko2 += kstr2; ko3 += kstr3; }       \
    VMA_;                                                                         \
    __builtin_amdgcn_s_barrier();                                                 \
    asm volatile("s_waitcnt lgkmcnt(0)" ::: "memory");                            \
    __builtin_amdgcn_sched_barrier(0);                                            \
    __builtin_amdgcn_s_setprio(1);                                                \
    _Pragma("unroll") for (int g_ = 0; g_ < 4; ++g_)                              \
      _Pragma("unroll") for (int m_ = 0; m_ < 4; ++m_)                            \
        acc[g_][4 + m_] = __builtin_amdgcn_mfma_f32_16x16x32_bf16(                \
            afr_[m_], bfr_[g_], acc[g_][4 + m_], 0, 0, 0);                        \
    __builtin_amdgcn_s_setprio(0);                                                \
    __builtin_amdgcn_s_barrier();                                                 \
  }

__global__ __launch_bounds__(512, 2)
void lstm_fused_kernel(const unsigned short* __restrict__ ws,
                       const float* __restrict__ c,
                       const float* __restrict__ bxf, const float* __restrict__ bhf,
                       const float* __restrict__ bxi, const float* __restrict__ bhi,
                       const float* __restrict__ bxo, const float* __restrict__ bho,
                       const float* __restrict__ bxc, const float* __restrict__ bhc,
                       float* __restrict__ out)
{
    __shared__ __align__(16) char lds[4 * STAGE_BYTES];   // 128 KB -> 1 block/CU

    const int tid  = threadIdx.x;
    const int w    = tid >> 6;     // 0..7
    const int lane = tid & 63;

    // XCD swizzle: 256 blocks, 8 XCDs -> each XCD owns 2 consecutive mx panels
    // (A never duplicated across XCDs; B broadcast is L3-served).
    const int bid  = blockIdx.x;
    const int wgid = (bid & 7) * 32 + (bid >> 3);
    const int mx  = wgid >> 4;          // [0,16)
    const int ny  = wgid & 15;          // [0,16)
    const int bm0 = mx * 256;
    const int bn0 = ny * 64;

    // staging: 32 packed chunks of 1 KB per stage; wave w owns ch = w*4+i.
    // ch<16: A chunk ch (row-group); ch>=16: b=ch-16 -> gate g=b>>2, col-grp b&3.
    const unsigned short* srcP[4];
    uint32_t loffA[4];
    uint32_t kstr0, kstr1, kstr2, kstr3;
    uint32_t ks_[4];
#pragma unroll
    for (int i = 0; i < 4; ++i) {
        const int ch = w * 4 + i;
        if (ch < 16) {
            // A chunk id = mx*1024 + KT*16 + ch
            srcP[i]  = ws + ((uint32_t)mx * 1024u + (uint32_t)ch) * 512u
                          + (uint32_t)lane * 8u;
            ks_[i]   = 16u * 512u;                 // elems per KT
            loffA[i] = (uint32_t)ch * 1024u;       // bytes within stage
        } else {
            const int b = ch - 16;
            // B chunk id = 16384 + (ny*16+b)*64 + KT
            srcP[i]  = ws + (16384u + ((uint32_t)ny * 16u + (uint32_t)b) * 64u) * 512u
                          + (uint32_t)lane * 8u;
            ks_[i]   = 512u;
            loffA[i] = 16384u + (uint32_t)b * 1024u;
        }
    }
    kstr0 = ks_[0]; kstr1 = ks_[1]; kstr2 = ks_[2]; kstr3 = ks_[3];

    const int wrow  = (w & 1) * 128;   // 2 m-halves of 128 rows
    const int wcol  = (w >> 1) * 16;   // col-group within each gate's 64
    const int lrc   = lane & 15;       // frag row (A) / col (B)
    const int lquad = lane >> 4;       // frag k-group (x8 elements)

    // reader-side swizzle (pack wrote the same image): slot = lquad^((r>>1)&3)
    const uint32_t kslot = ((uint32_t)lquad ^ (((uint32_t)lrc >> 1) & 3u)) * 8u;

    uint32_t aoff[8];
#pragma unroll
    for (int mt = 0; mt < 8; ++mt)
        aoff[mt] = (uint32_t)(((wrow >> 4) + mt) * 512) + (uint32_t)lrc * 32u + kslot;
    uint32_t boff[4];
#pragma unroll
    for (int g = 0; g < 4; ++g)
        boff[g] = 8192u + (uint32_t)((g * 4 + (w >> 1)) * 512) + (uint32_t)lrc * 32u + kslot;

    floatx4 acc[4][8];   // [gate][m-tile] = 128 fp32/lane
#pragma unroll
    for (int g = 0; g < 4; ++g)
#pragma unroll
        for (int mt = 0; mt < 8; ++mt)
            acc[g][mt] = (floatx4){0.f, 0.f, 0.f, 0.f};

    // prologue: stages 0,1,2 in flight (12 outstanding/wave)
#pragma unroll
    for (int t = 0; t < 3; ++t) {
#pragma unroll
        for (int i = 0; i < 4; ++i)
            GLL(srcP[i] + (uint32_t)t * ks_[i], lds + t * STAGE_BYTES + loffA[i]);
    }
    uint32_t ko0 = 3u * kstr0, ko1 = 3u * kstr1, ko2 = 3u * kstr2, ko3 = 3u * kstr3;
    VMW8;                              // stage 0 retired
    __builtin_amdgcn_s_barrier();

    for (int kt = 0; kt < 61; ++kt) ITER(kt, 1, VMW8);
    ITER(61, 0, VMW4);
    ITER(62, 0, VMW0);
    ITER(63, 0, VMNONE);

    // epilogue.  C/D layout: col = lane&15, row = (lane>>4)*4 + reg
    float* out_ct = out;
    float* out_ht = out + (size_t)M_DIM * H_DIM;
    {
        const int col = bn0 + wcol + lrc;
        const float bf_ = bxf[col] + bhf[col];
        const float bi_ = bxi[col] + bhi[col];
        const float bo_ = bxo[col] + bho[col];
        const float bc_ = bxc[col] + bhc[col];
#pragma unroll
        for (int mt = 0; mt < 8; ++mt) {
#pragma unroll
            for (int r = 0; r < 4; ++r) {
                const int row = bm0 + wrow + mt * 16 + lquad * 4 + r;
                const float gf = acc[0][mt][r] + bf_;
                const float gi = acc[1][mt][r] + bi_;
                const float go = acc[2][mt][r] + bo_;
                const float gc = acc[3][mt][r] + bc_;
                const float f    = fast_sigmoid(gf);
                const float ii   = fast_sigmoid(gi);
                const float o    = fast_sigmoid(go);
                const float ctil = fast_tanh(gc);
                const float cv   = c[(size_t)row * H_DIM + col];
                const float ctn  = f * cv + ctil * ii;
                const float htn  = fast_tanh(ctn) * o;
                out_ct[(size_t)row * H_DIM + col] = ctn;
                out_ht[(size_t)row * H_DIM + col] = htn;
            }
        }
    }
}

extern "C" void kernel_launch(void* const* d_in, const int* in_sizes, int n_in,
                              void* d_out, int out_size, void* d_ws, size_t ws_size,
                              hipStream_t stream) {
    (void)in_sizes; (void)n_in; (void)out_size; (void)ws_size;
    const float* x   = (const float*)d_in[0];
    const float* c   = (const float*)d_in[1];
    const float* h   = (const float*)d_in[2];
    const float* Wxf = (const float*)d_in[3];  const float* bxf = (const float*)d_in[4];
    const float* Whf = (const float*)d_in[5];  const float* bhf = (const float*)d_in[6];
    const float* Wxi = (const float*)d_in[7];  const float* bxi = (const float*)d_in[8];
    const float* Whi = (const float*)d_in[9];  const float* bhi = (const float*)d_in[10];
    const float* Wxo = (const float*)d_in[11]; const float* bxo = (const float*)d_in[12];
    const float* Who = (const float*)d_in[13]; const float* bho = (const float*)d_in[14];
    const float* Wxc = (const float*)d_in[15]; const float* bxc = (const float*)d_in[16];
    const float* Whc = (const float*)d_in[17]; const float* bhc = (const float*)d_in[18];
    float* out = (float*)d_out;
    unsigned short* ws = (unsigned short*)d_ws;   // 32768 chunks x 1 KB = 32 MB

    pack_bf16<<<8192, 256, 0, stream>>>(x, h,
        Wxf, Wxi, Wxo, Wxc, Whf, Whi, Who, Whc, ws);

    lstm_fused_kernel<<<256, 512, 0, stream>>>(ws, c,
        bxf, bhf, bxi, bhi, bxo, bho, bxc, bhc, out);
}